// Round 1
// baseline (204.895 us; speedup 1.0000x reference)
//
#include <hip/hip_runtime.h>

// CLRNetIoULoss: pred/target (NL, 72) fp32 -> scalar fp32 loss.
// loss = mean_over_rows(1 - iou_row) * LOSS_WEIGHT
// Memory-bound streaming reduction: 576 MB read -> floor ~91 us @ 6.3 TB/s.

#define NR 72
#define NR4 18               // float4 per row
#define BLOCK 256

__device__ __forceinline__ float4 ld4(const float4* p) { return *p; }

__global__ __launch_bounds__(BLOCK) void clrnet_iou_rows(
    const float* __restrict__ pred,
    const float* __restrict__ target,
    float* __restrict__ partial,   // one float per block
    int nl) {
  const int row = blockIdx.x * BLOCK + threadIdx.x;

  float loss = 0.0f;
  if (row < nl) {
    const float W = 15.0f / 800.0f;   // lane half-width
    const float4* p4 = reinterpret_cast<const float4*>(pred   + (size_t)row * NR);
    const float4* t4 = reinterpret_cast<const float4*>(target + (size_t)row * NR);

    float so = 0.0f;   // sum of overlap  (2w - |p-t| where both valid)
    float su = 0.0f;   // sum of union    (2w + |p-t| where both valid)
    int   tp = 0;      // both valid
    int   er = 0;      // exactly one valid (fp|fn == xor)

#pragma unroll
    for (int k = 0; k < NR4; ++k) {
      float4 p = ld4(p4 + k);
      float4 t = ld4(t4 + k);
#pragma unroll
      for (int j = 0; j < 4; ++j) {
        float pv = (&p.x)[j];
        float tv = (&t.x)[j];
        bool vp = (pv >= 0.0f) && (pv < 1.0f);
        bool vt = (tv >= 0.0f) && (tv < 1.0f);
        bool both = vp && vt;
        float d = fabsf(pv - tv);
        so += both ? (2.0f * W - d) : 0.0f;
        su += both ? (2.0f * W + d) : 0.0f;
        tp += both ? 1 : 0;
        er += (vp != vt) ? 1 : 0;
      }
    }

    float iou = so / (su + 1e-9f);
    if (tp > er && er > 0) {
      iou *= (1.0f - (float)er / ((float)tp + 1e-9f));
    }
    loss = 1.0f - iou;
  }

  // wave-64 shuffle reduce
#pragma unroll
  for (int off = 32; off > 0; off >>= 1)
    loss += __shfl_down(loss, off, 64);

  __shared__ float ws[BLOCK / 64];
  const int lane = threadIdx.x & 63;
  const int wid  = threadIdx.x >> 6;
  if (lane == 0) ws[wid] = loss;
  __syncthreads();
  if (threadIdx.x == 0) {
    float s = 0.0f;
#pragma unroll
    for (int w = 0; w < BLOCK / 64; ++w) s += ws[w];
    partial[blockIdx.x] = s;
  }
}

__global__ __launch_bounds__(256) void clrnet_iou_finish(
    const float* __restrict__ partial, int nparts, float* __restrict__ out,
    float inv_nl) {
  // single block; fp64 accumulation for deterministic, accurate final sum
  double acc = 0.0;
  for (int i = threadIdx.x; i < nparts; i += 256)
    acc += (double)partial[i];

  __shared__ double sd[256];
  sd[threadIdx.x] = acc;
  __syncthreads();
#pragma unroll
  for (int s = 128; s > 0; s >>= 1) {
    if (threadIdx.x < s) sd[threadIdx.x] += sd[threadIdx.x + s];
    __syncthreads();
  }
  if (threadIdx.x == 0) {
    const double LOSS_WEIGHT = 1.0;
    out[0] = (float)(sd[0] * (double)inv_nl * LOSS_WEIGHT);
  }
}

extern "C" void kernel_launch(void* const* d_in, const int* in_sizes, int n_in,
                              void* d_out, int out_size, void* d_ws, size_t ws_size,
                              hipStream_t stream) {
  const float* pred   = (const float*)d_in[0];
  const float* target = (const float*)d_in[1];
  float* out = (float*)d_out;

  const int nl = in_sizes[0] / NR;             // 1,000,000
  const int nblocks = (nl + BLOCK - 1) / BLOCK; // 3907

  float* partial = (float*)d_ws;               // nblocks floats of scratch

  clrnet_iou_rows<<<nblocks, BLOCK, 0, stream>>>(pred, target, partial, nl);
  clrnet_iou_finish<<<1, 256, 0, stream>>>(partial, nblocks, out,
                                           1.0f / (float)nl);
}

// Round 2
// 106.611 us; speedup vs baseline: 1.9219x; 1.9219x over previous
//
#include <hip/hip_runtime.h>

// CLRNetIoULoss: pred/target (NL, 72) fp32 -> scalar fp32 loss.
// Streaming reduction, 576 MB read -> floor ~91 us @ 6.3 TB/s achievable.
//
// R2: fully-coalesced loads (lane-stride 16B). Per-float4 partials
// {D=sum|p-t| over both-valid, packed tp/er counts} staged in LDS,
// then one thread per row does the nonlinear iou/penalty.
// so = 2W*tp - D ; su = 2W*tp + D  (algebraic reduction).

#define NR    72
#define NF4   18               // float4 per row
#define BLOCK 256
#define RPB   256              // rows per block
#define F4PB  (RPB * NF4)      // 4608 float4 per array per block
#define PAD   19               // padded row stride in LDS (breaks 8-way conflict)

__global__ __launch_bounds__(BLOCK, 4) void clrnet_iou_rows(
    const float4* __restrict__ pred4,
    const float4* __restrict__ tgt4,
    float* __restrict__ partial,   // one float per block
    int nl) {
  __shared__ float2 sbuf[RPB * PAD];   // {d_partial, bitcast(tp | er<<8)}

  const long long f4_total = (long long)nl * NF4;
  const long long base = (long long)blockIdx.x * F4PB;

  // ---- Phase 1: coalesced global -> per-float4 partials in LDS ----
#pragma unroll
  for (int k = 0; k < NF4; ++k) {
    const int iloc = k * BLOCK + threadIdx.x;          // 0..4607
    const long long g = base + iloc;
    float d = 0.0f;
    int   c = 0;
    if (g < f4_total) {
      float4 p = pred4[g];
      float4 t = tgt4[g];
#pragma unroll
      for (int j = 0; j < 4; ++j) {
        float pv = (&p.x)[j];
        float tv = (&t.x)[j];
        bool vp = (pv >= 0.0f) & (pv < 1.0f);
        bool vt = (tv >= 0.0f) & (tv < 1.0f);
        bool both = vp & vt;
        d += both ? fabsf(pv - tv) : 0.0f;
        c += (both ? 1 : 0) + ((vp != vt) ? 256 : 0);
      }
    }
    const int r = iloc / NF4;            // magic-mul div
    const int s = iloc - r * NF4;
    sbuf[r * PAD + s] = make_float2(d, __int_as_float(c));
  }
  __syncthreads();

  // ---- Phase 2: one thread per row, nonlinear part ----
  float loss = 0.0f;
  const long long row = base / NF4 + threadIdx.x;      // blockIdx*RPB + tid
  if (row < nl) {
    float D = 0.0f;
    int   c = 0;
    const int rbase = threadIdx.x * PAD;
#pragma unroll
    for (int j = 0; j < NF4; ++j) {
      float2 v = sbuf[rbase + j];
      D += v.x;
      c += __float_as_int(v.y);
    }
    const int tp = c & 0xff;
    const int er = c >> 8;
    const float W2 = 2.0f * (15.0f / 800.0f);
    const float ftp = (float)tp;
    float so = W2 * ftp - D;
    float su = W2 * ftp + D;
    float iou = so / (su + 1e-9f);
    if (tp > er && er > 0) {
      iou *= (1.0f - (float)er / (ftp + 1e-9f));
    }
    loss = 1.0f - iou;
  }

  // ---- block reduce of loss ----
#pragma unroll
  for (int off = 32; off > 0; off >>= 1)
    loss += __shfl_down(loss, off, 64);

  __shared__ float ws[BLOCK / 64];
  const int lane = threadIdx.x & 63;
  const int wid  = threadIdx.x >> 6;
  if (lane == 0) ws[wid] = loss;
  __syncthreads();
  if (threadIdx.x == 0) {
    float s = 0.0f;
#pragma unroll
    for (int w = 0; w < BLOCK / 64; ++w) s += ws[w];
    partial[blockIdx.x] = s;
  }
}

__global__ __launch_bounds__(256) void clrnet_iou_finish(
    const float* __restrict__ partial, int nparts, float* __restrict__ out,
    float inv_nl) {
  // single block; fp64 accumulation for deterministic, accurate final sum
  double acc = 0.0;
  for (int i = threadIdx.x; i < nparts; i += 256)
    acc += (double)partial[i];

  __shared__ double sd[256];
  sd[threadIdx.x] = acc;
  __syncthreads();
#pragma unroll
  for (int s = 128; s > 0; s >>= 1) {
    if (threadIdx.x < s) sd[threadIdx.x] += sd[threadIdx.x + s];
    __syncthreads();
  }
  if (threadIdx.x == 0) {
    const double LOSS_WEIGHT = 1.0;
    out[0] = (float)(sd[0] * (double)inv_nl * LOSS_WEIGHT);
  }
}

extern "C" void kernel_launch(void* const* d_in, const int* in_sizes, int n_in,
                              void* d_out, int out_size, void* d_ws, size_t ws_size,
                              hipStream_t stream) {
  const float4* pred4 = (const float4*)d_in[0];
  const float4* tgt4  = (const float4*)d_in[1];
  float* out = (float*)d_out;

  const int nl = in_sizes[0] / NR;               // 1,000,000
  const int nblocks = (nl + RPB - 1) / RPB;      // 3907

  float* partial = (float*)d_ws;                 // nblocks floats of scratch

  clrnet_iou_rows<<<nblocks, BLOCK, 0, stream>>>(pred4, tgt4, partial, nl);
  clrnet_iou_finish<<<1, 256, 0, stream>>>(partial, nblocks, out,
                                           1.0f / (float)nl);
}